// Round 1
// baseline (270.756 us; speedup 1.0000x reference)
//
#include <hip/hip_runtime.h>
#include <hip/hip_bf16.h>

// Problem constants (fixed by the reference)
#define NROWS   200000
#define DSP     64      // spatial width
#define DST     131     // structural width
#define DOUT    256
#define K1PAD   224     // 195 padded to 7*32
#define K2PAD   160     // 131 padded to 5*32
#define NK1     7
#define NK2     5
#define BM      64      // rows per block
#define NBLK    (NROWS / BM)   // 3125 exactly

typedef short bf8   __attribute__((ext_vector_type(8)));   // 8 bf16 (4 VGPRs)
typedef float f32x4 __attribute__((ext_vector_type(4)));

// f32 -> bf16 (RNE) on raw bits
__device__ __forceinline__ short f2bf(float x) {
    unsigned u = __float_as_uint(x);
    unsigned r = (u + 0x7fffu + ((u >> 16) & 1u)) >> 16;
    return (short)r;
}

// ---------------------------------------------------------------------------
// Pack weights into MFMA B-fragment order:
//   entry(ks, cb, lane, j) = W[n][k], n = cb*16 + (lane&15), k = ks*32 + (lane>>4)*8 + j
//   (0 beyond the real K). Layout offset = ((ks*16+cb)*64 + lane)*8 + j.
// W1p: 7*16*64*8 = 57344 entries (W_comb, K=195)
// W2p: 5*16*64*8 = 40960 entries (W_agg,  K=131)
// ---------------------------------------------------------------------------
__global__ __launch_bounds__(256) void wprep(const float* __restrict__ Wc,
                                             const float* __restrict__ Wa,
                                             short* __restrict__ w1p,
                                             short* __restrict__ w2p) {
    int idx = blockIdx.x * 256 + threadIdx.x;
    if (idx < 57344) {
        int j  = idx & 7;
        int l  = (idx >> 3) & 63;
        int cb = (idx >> 9) & 15;
        int ks = idx >> 13;
        int k  = ks * 32 + (l >> 4) * 8 + j;
        int n  = cb * 16 + (l & 15);
        float v = (k < 195) ? Wc[n * 195 + k] : 0.0f;
        w1p[idx] = f2bf(v);
    } else {
        int id2 = idx - 57344;
        if (id2 < 40960) {
            int j  = id2 & 7;
            int l  = (id2 >> 3) & 63;
            int cb = (id2 >> 9) & 15;
            int ks = id2 >> 13;
            int k  = ks * 32 + (l >> 4) * 8 + j;
            int n  = cb * 16 + (l & 15);
            float v = (k < 131) ? Wa[n * 131 + k] : 0.0f;
            w2p[id2] = f2bf(v);
        }
    }
}

// ---------------------------------------------------------------------------
// Shared MFMA core: given an LDS A-tile [64][LDK_PAD] (bf16-as-short) holding
// K = NK*32 valid (zero-padded) columns, compute the 64x256 output tile.
// ---------------------------------------------------------------------------
template <int NK, int LDPAD>
__device__ __forceinline__ void mfma_tile_and_store(
        const short (*lds)[LDPAD],
        const short* __restrict__ wp,       // fragment-packed B
        const float* __restrict__ bias,     // [256]
        float* __restrict__ out,            // output base (row-major [NROWS][256])
        int r0, int t) {
    const int wave = t >> 6;
    const int l    = t & 63;
    const int lr   = l & 15;   // A-row / D-col
    const int lk   = l >> 4;   // k-group / D-row-group

    f32x4 acc[4][4];
    #pragma unroll
    for (int m = 0; m < 4; ++m)
        #pragma unroll
        for (int n = 0; n < 4; ++n)
            acc[m][n] = (f32x4){0.f, 0.f, 0.f, 0.f};

    #pragma unroll
    for (int ks = 0; ks < NK; ++ks) {
        bf8 a[4], bb[4];
        #pragma unroll
        for (int m = 0; m < 4; ++m)
            a[m] = *(const bf8*)&lds[m * 16 + lr][ks * 32 + lk * 8];
        #pragma unroll
        for (int n = 0; n < 4; ++n) {
            int cb = wave * 4 + n;
            bb[n] = *(const bf8*)(wp + (((ks * 16 + cb) * 64 + l) << 3));
        }
        #pragma unroll
        for (int m = 0; m < 4; ++m)
            #pragma unroll
            for (int n = 0; n < 4; ++n)
                acc[m][n] = __builtin_amdgcn_mfma_f32_16x16x32_bf16(
                                a[m], bb[n], acc[m][n], 0, 0, 0);
    }

    #pragma unroll
    for (int n = 0; n < 4; ++n) {
        int col = wave * 64 + n * 16 + lr;
        float bv = bias[col];
        #pragma unroll
        for (int m = 0; m < 4; ++m) {
            #pragma unroll
            for (int r = 0; r < 4; ++r) {
                int row = m * 16 + lk * 4 + r;
                out[(size_t)(r0 + row) * DOUT + col] = acc[m][n][r] + bv;
            }
        }
    }
}

// ---------------------------------------------------------------------------
// GEMM1: out1 = [spatial | structural] @ W_comb^T + b_comb
// ---------------------------------------------------------------------------
__global__ __launch_bounds__(256) void gemm1(const float* __restrict__ spatial,
                                             const float* __restrict__ structural,
                                             const short* __restrict__ w1p,
                                             const float* __restrict__ bias,
                                             float* __restrict__ out) {
    __shared__ short lds[BM][K1PAD + 8];   // stride 232 shorts = 464 B
    const int t  = threadIdx.x;
    const int r0 = blockIdx.x * BM;

    // stage spatial -> cols 0..63 (fully coalesced float4)
    {
        int row = t >> 2;
        int c0  = (t & 3) * 16;
        const float4* sp = (const float4*)(spatial + (size_t)(r0 + row) * DSP + c0);
        #pragma unroll
        for (int i = 0; i < 4; ++i) {
            float4 v = sp[i];
            int c = c0 + i * 4;
            lds[row][c + 0] = f2bf(v.x);
            lds[row][c + 1] = f2bf(v.y);
            lds[row][c + 2] = f2bf(v.z);
            lds[row][c + 3] = f2bf(v.w);
        }
    }
    // stage structural (flat, fully coalesced float4) -> cols 64..194
    {
        const size_t base = (size_t)r0 * DST;   // r0*131, 16B-aligned (r0 mult of 64)
        for (int i = 0; i < 9; ++i) {
            int q = i * 256 + t;                 // float4 index, 2096 total
            if (q < (BM * DST) / 4) {
                float4 v = *(const float4*)(structural + base + (size_t)q * 4);
                int e0 = q * 4;
                #pragma unroll
                for (int u = 0; u < 4; ++u) {
                    int e   = e0 + u;
                    int row = e / DST;
                    int col = e - row * DST;
                    lds[row][DSP + col] = f2bf((&v.x)[u]);
                }
            }
        }
    }
    // zero-pad cols 195..223
    for (int i = t; i < BM * 32; i += 256) {
        int row = i >> 5, c = 192 + (i & 31);
        if (c >= 195) lds[row][c] = 0;
    }
    __syncthreads();

    mfma_tile_and_store<NK1, K1PAD + 8>(lds, w1p, bias, out, r0, t);
}

// ---------------------------------------------------------------------------
// GEMM2: agg = 0.25*(structural + sum of 3 gathered rows); out2 = agg @ W_agg^T + b_agg
// ---------------------------------------------------------------------------
__global__ __launch_bounds__(256) void gemm2(const float* __restrict__ structural,
                                             const int* __restrict__ neigh,
                                             const short* __restrict__ w2p,
                                             const float* __restrict__ bias,
                                             float* __restrict__ out) {
    __shared__ short lds[BM][K2PAD + 8];   // stride 168 shorts = 336 B
    const int t  = threadIdx.x;
    const int r0 = blockIdx.x * BM;

    {
        int row = t >> 2;       // 0..63, 4 threads per row
        int j   = t & 3;
        size_t rg = (size_t)(r0 + row);
        const float* s0 = structural + rg * DST;
        int n0 = neigh[rg * 3 + 0];
        int n1 = neigh[rg * 3 + 1];
        int n2 = neigh[rg * 3 + 2];
        const float* s1 = structural + (size_t)n0 * DST;
        const float* s2 = structural + (size_t)n1 * DST;
        const float* s3 = structural + (size_t)n2 * DST;
        for (int c = j; c < DST; c += 4) {
            float v = s0[c] + s1[c] + s2[c] + s3[c];
            lds[row][c] = f2bf(v * 0.25f);
        }
        for (int c = DST + j; c < K2PAD; c += 4) lds[row][c] = 0;
    }
    __syncthreads();

    mfma_tile_and_store<NK2, K2PAD + 8>(lds, w2p, bias, out, r0, t);
}

// ---------------------------------------------------------------------------
extern "C" void kernel_launch(void* const* d_in, const int* in_sizes, int n_in,
                              void* d_out, int out_size, void* d_ws, size_t ws_size,
                              hipStream_t stream) {
    const float* spatial    = (const float*)d_in[0];
    const float* structural = (const float*)d_in[1];
    const int*   neighbour  = (const int*)  d_in[2];
    const float* W_agg      = (const float*)d_in[3];
    const float* b_agg      = (const float*)d_in[4];
    const float* W_comb     = (const float*)d_in[5];
    const float* b_comb     = (const float*)d_in[6];

    float* out1 = (float*)d_out;
    float* out2 = out1 + (size_t)NROWS * DOUT;

    short* w1p = (short*)d_ws;          // 57344 shorts
    short* w2p = w1p + 57344;           // 40960 shorts  (total 196608 B)

    wprep<<<384, 256, 0, stream>>>(W_comb, W_agg, w1p, w2p);
    gemm1<<<NBLK, 256, 0, stream>>>(spatial, structural, w1p, b_comb, out1);
    gemm2<<<NBLK, 256, 0, stream>>>(structural, neighbour, w2p, b_agg, out2);
}

// Round 2
// 211.586 us; speedup vs baseline: 1.2797x; 1.2797x over previous
//
#include <hip/hip_runtime.h>
#include <hip/hip_bf16.h>

// Problem constants (fixed by the reference)
#define NROWS   200000
#define DSP     64      // spatial width
#define DST     131     // structural width
#define DOUT    256
#define K1PAD   224     // 195 padded to 7*32
#define K2PAD   160     // 131 padded to 5*32
#define NK1     7
#define NK2     5
#define BM      64      // rows per block
#define NBLK    (NROWS / BM)   // 3125 exactly
#define LD1     (K1PAD + 8)    // 232 shorts = 464 B row stride
#define LD2     (K2PAD + 8)    // 168 shorts = 336 B row stride

typedef short bf8   __attribute__((ext_vector_type(8)));   // 8 bf16 (4 VGPRs)
typedef float f32x4 __attribute__((ext_vector_type(4)));

// f32 -> bf16 (RNE) on raw bits
__device__ __forceinline__ unsigned short f2bf(float x) {
    unsigned u = __float_as_uint(x);
    unsigned r = (u + 0x7fffu + ((u >> 16) & 1u)) >> 16;
    return (unsigned short)r;
}
__device__ __forceinline__ unsigned pack2(unsigned short lo, unsigned short hi) {
    return (unsigned)lo | ((unsigned)hi << 16);
}

// ---------------------------------------------------------------------------
// Pack weights into MFMA B-fragment order:
//   entry(ks, cb, lane, j) = W[n][k], n = cb*16 + (lane&15), k = ks*32 + (lane>>4)*8 + j
// ---------------------------------------------------------------------------
__global__ __launch_bounds__(256) void wprep(const float* __restrict__ Wc,
                                             const float* __restrict__ Wa,
                                             short* __restrict__ w1p,
                                             short* __restrict__ w2p) {
    int idx = blockIdx.x * 256 + threadIdx.x;
    if (idx < 57344) {
        int j  = idx & 7;
        int l  = (idx >> 3) & 63;
        int cb = (idx >> 9) & 15;
        int ks = idx >> 13;
        int k  = ks * 32 + (l >> 4) * 8 + j;
        int n  = cb * 16 + (l & 15);
        float v = (k < 195) ? Wc[n * 195 + k] : 0.0f;
        w1p[idx] = (short)f2bf(v);
    } else {
        int id2 = idx - 57344;
        if (id2 < 40960) {
            int j  = id2 & 7;
            int l  = (id2 >> 3) & 63;
            int cb = (id2 >> 9) & 15;
            int ks = id2 >> 13;
            int k  = ks * 32 + (l >> 4) * 8 + j;
            int n  = cb * 16 + (l & 15);
            float v = (k < 131) ? Wa[n * 131 + k] : 0.0f;
            w2p[id2] = (short)f2bf(v);
        }
    }
}

// ---------------------------------------------------------------------------
// MFMA core: LDS A-tile [64][LDPAD] (bf16), fragment-packed B in wp,
// computes the 64x256 tile and stores f32 + bias.
// ---------------------------------------------------------------------------
template <int NK, int LDPAD>
__device__ __forceinline__ void mfma_tile_and_store(
        const short (*lds)[LDPAD],
        const short* __restrict__ wp,
        const float* __restrict__ bias,
        float* __restrict__ out,
        int r0, int t) {
    const int wave = t >> 6;
    const int l    = t & 63;
    const int lr   = l & 15;   // A-row / D-col
    const int lk   = l >> 4;   // k-group / D-row-group

    f32x4 acc[4][4];
    #pragma unroll
    for (int m = 0; m < 4; ++m)
        #pragma unroll
        for (int n = 0; n < 4; ++n)
            acc[m][n] = (f32x4){0.f, 0.f, 0.f, 0.f};

    #pragma unroll
    for (int ks = 0; ks < NK; ++ks) {
        bf8 a[4], bb[4];
        #pragma unroll
        for (int m = 0; m < 4; ++m)
            a[m] = *(const bf8*)&lds[m * 16 + lr][ks * 32 + lk * 8];
        #pragma unroll
        for (int n = 0; n < 4; ++n) {
            int cb = wave * 4 + n;
            bb[n] = *(const bf8*)(wp + (((ks * 16 + cb) * 64 + l) << 3));
        }
        #pragma unroll
        for (int m = 0; m < 4; ++m)
            #pragma unroll
            for (int n = 0; n < 4; ++n)
                acc[m][n] = __builtin_amdgcn_mfma_f32_16x16x32_bf16(
                                a[m], bb[n], acc[m][n], 0, 0, 0);
    }

    #pragma unroll
    for (int n = 0; n < 4; ++n) {
        int col = wave * 64 + n * 16 + lr;
        float bv = bias[col];
        #pragma unroll
        for (int m = 0; m < 4; ++m) {
            #pragma unroll
            for (int r = 0; r < 4; ++r) {
                int row = m * 16 + lk * 4 + r;
                out[(size_t)(r0 + row) * DOUT + col] = acc[m][n][r] + bv;
            }
        }
    }
}

// ---------------------------------------------------------------------------
// Fused kernel: stage A1 ([spatial|structural], bf16) and A2 (agg, bf16)
// for 64 rows, then two MFMA tile-computes -> out1, out2.
// ---------------------------------------------------------------------------
__global__ __launch_bounds__(256) void fused(const float* __restrict__ spatial,
                                             const float* __restrict__ structural,
                                             const int*   __restrict__ neigh,
                                             const short* __restrict__ w1p,
                                             const short* __restrict__ w2p,
                                             const float* __restrict__ b_comb,
                                             const float* __restrict__ b_agg,
                                             float* __restrict__ out1,
                                             float* __restrict__ out2) {
    __shared__ short lds1[BM][LD1];
    __shared__ short lds2[BM][LD2];
    const int t  = threadIdx.x;
    const int r0 = blockIdx.x * BM;

    // ---- zero-pad tails: lds1 cols 195..223, lds2 cols 131..159 ----
    {
        int row = t >> 2;            // 64 rows, 4 threads each
        int j   = t & 3;
        // lds1: 29 pad cols (195..223)
        for (int c = 195 + j; c < K1PAD; c += 4) lds1[row][c] = 0;
        // lds2: 29 pad cols (131..159)
        for (int c = 131 + j; c < K2PAD; c += 4) lds2[row][c] = 0;
    }

    // ---- stage spatial -> lds1 cols 0..63 (float4 loads, 8B LDS writes) ----
    {
        int h  = t & 15;             // 16 lanes per row-slot
        int sl = t >> 4;             // 16 slots
        #pragma unroll
        for (int p = 0; p < 4; ++p) {
            int row = sl + 16 * p;
            float4 v = *(const float4*)(spatial + (size_t)(r0 + row) * DSP + 4 * h);
            uint2 w;
            w.x = pack2(f2bf(v.x), f2bf(v.y));
            w.y = pack2(f2bf(v.z), f2bf(v.w));
            *(uint2*)&lds1[row][4 * h] = w;
        }
    }

    // ---- stage structural self -> lds1 cols 64..194, agg -> lds2 cols 0..130 ----
    {
        int g = t & 31;              // 32 lanes per row-slot, strided cols
        int s = t >> 5;              // 8 slots
        #pragma unroll
        for (int p = 0; p < 8; ++p) {
            int rr = s + 8 * p;
            size_t r = (size_t)(r0 + rr);
            const float* s0 = structural + r * DST;
            const int*   nb = neigh + r * 3;
            int n0 = nb[0], n1 = nb[1], n2 = nb[2];
            const float* p1 = structural + (size_t)n0 * DST;
            const float* p2 = structural + (size_t)n1 * DST;
            const float* p3 = structural + (size_t)n2 * DST;
            #pragma unroll
            for (int i = 0; i < 4; ++i) {
                int c = g + 32 * i;          // 0..127, 128B coalesced per slot
                float v0 = s0[c];
                float a  = v0 + p1[c] + p2[c] + p3[c];
                lds1[rr][DSP + c] = (short)f2bf(v0);
                lds2[rr][c]       = (short)f2bf(a * 0.25f);
            }
            if (g < 3) {                     // tail cols 128..130
                int c = 128 + g;
                float v0 = s0[c];
                float a  = v0 + p1[c] + p2[c] + p3[c];
                lds1[rr][DSP + c] = (short)f2bf(v0);
                lds2[rr][c]       = (short)f2bf(a * 0.25f);
            }
        }
    }
    __syncthreads();

    mfma_tile_and_store<NK1, LD1>(lds1, w1p, b_comb, out1, r0, t);
    mfma_tile_and_store<NK2, LD2>(lds2, w2p, b_agg, out2, r0, t);
}

// ---------------------------------------------------------------------------
extern "C" void kernel_launch(void* const* d_in, const int* in_sizes, int n_in,
                              void* d_out, int out_size, void* d_ws, size_t ws_size,
                              hipStream_t stream) {
    const float* spatial    = (const float*)d_in[0];
    const float* structural = (const float*)d_in[1];
    const int*   neighbour  = (const int*)  d_in[2];
    const float* W_agg      = (const float*)d_in[3];
    const float* b_agg      = (const float*)d_in[4];
    const float* W_comb     = (const float*)d_in[5];
    const float* b_comb     = (const float*)d_in[6];

    float* out1 = (float*)d_out;
    float* out2 = out1 + (size_t)NROWS * DOUT;

    short* w1p = (short*)d_ws;          // 57344 shorts
    short* w2p = w1p + 57344;           // 40960 shorts

    wprep<<<384, 256, 0, stream>>>(W_comb, W_agg, w1p, w2p);
    fused<<<NBLK, 256, 0, stream>>>(spatial, structural, neighbour,
                                    w1p, w2p, b_comb, b_agg, out1, out2);
}